// Round 4
// baseline (701.302 us; speedup 1.0000x reference)
//
#include <hip/hip_runtime.h>
#include <math.h>

#define N_TOTAL 40960
#define M_EV    4096
#define KNN     32
#define FEAT    192   // CIN + 2*PDIM

typedef float f32v32 __attribute__((ext_vector_type(32)));
typedef int   i32v32 __attribute__((ext_vector_type(32)));

__device__ __forceinline__ float dot4f(float4 a, float4 b) {
    return fmaf(a.w, b.w, fmaf(a.z, b.z, fmaf(a.y, b.y, a.x * b.x)));
}

// ---------------------------------------------------------------------------
// Register-resident top-K list. Max slot tracked as a ONE-HOT MASK, never an
// index: the per-element select tests (onehot & (1u<<e)) with a compile-time
// constant, which LLVM cannot fold back into a dynamic insertelement (the
// e==maxpos form did fold, and dynamic insertelement lowers via scratch —
// that was rounds 2/3's VGPR_Count=64 + 55 MB WRITE_SIZE spill signature).
// ---------------------------------------------------------------------------
__device__ __forceinline__ void list_rescan(const f32v32 &ld, float &curmax, unsigned &onehot)
{
    float t0[16];
#pragma unroll
    for (int e = 0; e < 16; ++e) t0[e] = fmaxf(ld[2*e], ld[2*e+1]);
    float t1[8];
#pragma unroll
    for (int e = 0; e < 8; ++e) t1[e] = fmaxf(t0[2*e], t0[2*e+1]);
    float t2[4];
#pragma unroll
    for (int e = 0; e < 4; ++e) t2[e] = fmaxf(t1[2*e], t1[2*e+1]);
    float m = fmaxf(fmaxf(t2[0], t2[1]), fmaxf(t2[2], t2[3]));
    unsigned msk = 0u;
#pragma unroll
    for (int e = 0; e < 32; ++e) msk |= (ld[e] == m) ? (1u << e) : 0u;
    curmax = m;
    onehot = msk & (0u - msk);          // lowest set bit, as a mask (no index!)
}

__device__ __forceinline__ void list_insert(f32v32 &ld, i32v32 &li,
                                            float &curmax, unsigned &onehot,
                                            float d, int ix)
{
#pragma unroll
    for (int e = 0; e < 32; ++e) {
        bool s = (onehot & (1u << e)) != 0u;
        ld[e] = s ? d  : ld[e];
        li[e] = s ? ix : li[e];
    }
    list_rescan(ld, curmax, onehot);
}

// ---------------------------------------------------------------------------
// Kernel 1: space = x@W_space + b_space  [N,4];  prop = x@W_prop + b_prop [N,64]
// ---------------------------------------------------------------------------
__global__ __launch_bounds__(256) void k_linear(
    const float* __restrict__ x,
    const float* __restrict__ Wp, const float* __restrict__ bp,
    const float* __restrict__ Ws, const float* __restrict__ bs,
    float* __restrict__ prop, float* __restrict__ space)
{
    __shared__ float xs[16 * 64];
    const int t = threadIdx.x;
    const int rowbase = blockIdx.x * 16;

    {
        float4 v = *(const float4*)(x + rowbase * 64 + t * 4);
        *(float4*)(xs + t * 4) = v;
    }
    __syncthreads();

    const int j  = t & 63;
    const int rg = t >> 6;
    float a0 = 0.f, a1 = 0.f, a2 = 0.f, a3 = 0.f;
#pragma unroll 8
    for (int c = 0; c < 64; ++c) {
        float w = Wp[c * 64 + j];
        a0 = fmaf(xs[(rg * 4 + 0) * 64 + c], w, a0);
        a1 = fmaf(xs[(rg * 4 + 1) * 64 + c], w, a1);
        a2 = fmaf(xs[(rg * 4 + 2) * 64 + c], w, a2);
        a3 = fmaf(xs[(rg * 4 + 3) * 64 + c], w, a3);
    }
    const float bj = bp[j];
    prop[(rowbase + rg * 4 + 0) * 64 + j] = a0 + bj;
    prop[(rowbase + rg * 4 + 1) * 64 + j] = a1 + bj;
    prop[(rowbase + rg * 4 + 2) * 64 + j] = a2 + bj;
    prop[(rowbase + rg * 4 + 3) * 64 + j] = a3 + bj;

    if (t < 64) {
        const int r = t >> 2, s = t & 3;
        float a = 0.f;
#pragma unroll 8
        for (int c = 0; c < 64; ++c)
            a = fmaf(xs[r * 64 + c], Ws[c * 4 + s], a);
        space[(rowbase + r) * 4 + s] = a + bs[s];
    }
}

// ---------------------------------------------------------------------------
// Kernel 2a: per-half exact partial kNN (structure unchanged from round 3;
// only the list representation changed).
// ---------------------------------------------------------------------------
#define QB    64
#define CHUNK 512
#define KTILE 64
#define QCAP  16

__global__ __launch_bounds__(256) void k_knn1(
    const float4* __restrict__ space4,
    unsigned* __restrict__ g_thr,
    float* __restrict__ part_d, int* __restrict__ part_i)
{
    __shared__ float4   s_c[4 * KTILE];      // 4096 B
    __shared__ float    s_sq[4 * KTILE];     // 1024 B
    __shared__ float    s_bd[QCAP * 256];    // 16384 B (aliased as merge pool_d)
    __shared__ int      s_bi[QCAP * 256];    // 16384 B (aliased as merge pool_i)
    __shared__ unsigned s_thr[QB];           // 256 B

    const int t = threadIdx.x;
    const int w = t >> 6;
    const int l = t & 63;
    const int grp  = blockIdx.x >> 1;
    const int half = blockIdx.x & 1;
    const int qbase = grp * QB;
    const int q = qbase + l;
    const int ebase = (qbase / M_EV) * M_EV;
    const int cbase0 = half * 2048 + w * CHUNK;

    if (t < QB) s_thr[t] = 0x7f800000u;
    __syncthreads();

    const float4 qc = space4[q];
    const float sqq = dot4f(qc, qc);

    f32v32 ld; i32v32 li;
#pragma unroll
    for (int e = 0; e < 32; ++e) { ld[e] = INFINITY; li[e] = 0; }
    float curmax = INFINITY; unsigned onehot = 1u;
    int cnt = 0;
    float thrA = INFINITY;

    float4 nx = space4[ebase + cbase0 + l];

#pragma unroll 1
    for (int tb = 0; tb < CHUNK / KTILE; ++tb) {
        const int cb = cbase0 + tb * KTILE;
        s_c[w * KTILE + l]  = nx;
        s_sq[w * KTILE + l] = dot4f(nx, nx);
        if (tb + 1 < CHUNK / KTILE)
            nx = space4[ebase + cb + KTILE + l];
        thrA = fminf(curmax, __uint_as_float(s_thr[l]));

#pragma unroll 1
        for (int jj = 0; jj < KTILE; jj += 4) {
            float d[4];
#pragma unroll
            for (int u = 0; u < 4; ++u) {
                float4 c = s_c[w * KTILE + jj + u];
                d[u] = fmaf(-2.0f, dot4f(qc, c), sqq + s_sq[w * KTILE + jj + u]);
            }
#pragma unroll
            for (int u = 0; u < 4; ++u) {
                if (d[u] < thrA) {                 // strict <: earlier idx wins ties
                    s_bd[cnt * 256 + t] = d[u];
                    s_bi[cnt * 256 + t] = cb + jj + u;
                    cnt++;
                }
            }
            if (__any(cnt > QCAP - 4)) {           // wave-collective packed drain
                float gate = fminf(curmax, __uint_as_float(s_thr[l]));
#pragma unroll 1
                for (int b = 0; b < cnt; ++b) {
                    float dd = s_bd[b * 256 + t];
                    if (dd < gate) {
                        list_insert(ld, li, curmax, onehot, dd, s_bi[b * 256 + t]);
                        gate = fminf(curmax, gate);
                    }
                }
                cnt = 0;
                if (curmax < 3.0e38f) {
                    unsigned mb = __float_as_uint(fmaxf(curmax, 0.0f));
                    atomicMin(&s_thr[l], mb);
                    unsigned old = atomicMin(&g_thr[q], mb);   // publish + fresh read
                    atomicMin(&s_thr[l], old);
                }
                thrA = fminf(curmax, __uint_as_float(s_thr[l]));
            }
        }
    }
    {   // final drain
        float gate = fminf(curmax, __uint_as_float(s_thr[l]));
#pragma unroll 1
        for (int b = 0; b < cnt; ++b) {
            float dd = s_bd[b * 256 + t];
            if (dd < gate) {
                list_insert(ld, li, curmax, onehot, dd, s_bi[b * 256 + t]);
                gate = fminf(curmax, gate);
            }
        }
    }

    // ---- hierarchical in-block merge (pool aliases s_bd/s_bi) ----
    __syncthreads();
    if (w >= 2) {
#pragma unroll
        for (int e = 0; e < 32; ++e) {
            s_bd[((w - 2) * 32 + e) * 64 + l] = ld[e];
            s_bi[((w - 2) * 32 + e) * 64 + l] = li[e];
        }
    }
    __syncthreads();
    if (w < 2) {
#pragma unroll 1
        for (int j = 0; j < 32; ++j) {
            float dd = s_bd[(w * 32 + j) * 64 + l];
            if (dd < curmax)
                list_insert(ld, li, curmax, onehot, dd, s_bi[(w * 32 + j) * 64 + l]);
        }
    }
    __syncthreads();
    if (w == 1) {
#pragma unroll
        for (int e = 0; e < 32; ++e) {
            s_bd[e * 64 + l] = ld[e];
            s_bi[e * 64 + l] = li[e];
        }
    }
    __syncthreads();
    if (w == 0) {
#pragma unroll 1
        for (int j = 0; j < 32; ++j) {
            float dd = s_bd[j * 64 + l];
            if (dd < curmax)
                list_insert(ld, li, curmax, onehot, dd, s_bi[j * 64 + l]);
        }
        const int q2h = (q << 1) | half;
#pragma unroll
        for (int e = 0; e < 32; ++e) {
            part_d[e * (N_TOTAL * 2) + q2h] = ld[e];
            part_i[e * (N_TOTAL * 2) + q2h] = ebase + li[e];
        }
    }
}

// ---------------------------------------------------------------------------
// Kernel 2b: merge the two per-half top-32 partials -> exact top-32 + weights.
// ---------------------------------------------------------------------------
__global__ __launch_bounds__(256) void k_knn2(
    const float* __restrict__ part_d, const int* __restrict__ part_i,
    int* __restrict__ knn_idx, float* __restrict__ knn_w)
{
    const int q  = blockIdx.x * 256 + threadIdx.x;
    const int q2 = q << 1;

    f32v32 ld; i32v32 li;
#pragma unroll
    for (int e = 0; e < 32; ++e) {
        ld[e] = part_d[e * (N_TOTAL * 2) + q2];
        li[e] = part_i[e * (N_TOTAL * 2) + q2];
    }
    float curmax; unsigned onehot;
    list_rescan(ld, curmax, onehot);

#pragma unroll 1
    for (int j = 0; j < 32; ++j) {
        float dd = part_d[j * (N_TOTAL * 2) + q2 + 1];
        if (dd < curmax)
            list_insert(ld, li, curmax, onehot, dd, part_i[j * (N_TOTAL * 2) + q2 + 1]);
    }

#pragma unroll
    for (int e = 0; e < 32; ++e) {
        knn_idx[e * N_TOTAL + q] = li[e];
        knn_w[e * N_TOTAL + q]   = __expf(-10.0f * fmaxf(ld[e], 0.0f));
    }
}

// ---------------------------------------------------------------------------
// Kernel 3: weighted gather + mean/max over K
// ---------------------------------------------------------------------------
__global__ __launch_bounds__(256) void k_agg(
    const float* __restrict__ prop,
    const int* __restrict__ knn_idx, const float* __restrict__ knn_w,
    float* __restrict__ fmean, float* __restrict__ fmax)
{
    const int t = threadIdx.x;
    const int p = t & 63;
    const int q = blockIdx.x * 4 + (t >> 6);

    float acc = 0.f, mx = -INFINITY;
#pragma unroll 8
    for (int e = 0; e < KNN; ++e) {
        int   ix = knn_idx[e * N_TOTAL + q];
        float w  = knn_w[e * N_TOTAL + q];
        float g  = w * prop[(size_t)ix * 64 + p];
        acc += g;
        mx = fmaxf(mx, g);
    }
    fmean[(size_t)q * 64 + p] = acc * (1.0f / 32.0f);
    fmax[(size_t)q * 64 + p]  = mx;
}

// ---------------------------------------------------------------------------
// Kernel 4: out = relu([x | fmean | fmax] @ W_out + b_out)
// ---------------------------------------------------------------------------
__global__ __launch_bounds__(256) void k_out(
    const float* __restrict__ x,
    const float* __restrict__ fmean, const float* __restrict__ fmax,
    const float* __restrict__ Wo, const float* __restrict__ bo,
    float* __restrict__ out)
{
    __shared__ float fs[16 * FEAT];
    const int t = threadIdx.x;
    const int qbase = blockIdx.x * 16;

#pragma unroll
    for (int u = 0; u < 12; ++u) {
        int f = u * 256 + t;
        int r = f / FEAT;
        int i = f - r * FEAT;
        float v;
        if (i < 64)        v = x[(size_t)(qbase + r) * 64 + i];
        else if (i < 128)  v = fmean[(size_t)(qbase + r) * 64 + (i - 64)];
        else               v = fmax[(size_t)(qbase + r) * 64 + (i - 128)];
        fs[f] = v;
    }
    __syncthreads();

    const int c  = t & 127;
    const int rg = t >> 7;
    float acc[8] = {0.f, 0.f, 0.f, 0.f, 0.f, 0.f, 0.f, 0.f};

#pragma unroll 4
    for (int i = 0; i < FEAT; ++i) {
        float w = Wo[i * 128 + c];
#pragma unroll
        for (int r = 0; r < 8; ++r)
            acc[r] = fmaf(fs[(rg * 8 + r) * FEAT + i], w, acc[r]);
    }
    const float bc = bo[c];
#pragma unroll
    for (int r = 0; r < 8; ++r)
        out[(size_t)(qbase + rg * 8 + r) * 128 + c] = fmaxf(acc[r] + bc, 0.0f);
}

// ---------------------------------------------------------------------------
extern "C" void kernel_launch(void* const* d_in, const int* in_sizes, int n_in,
                              void* d_out, int out_size, void* d_ws, size_t ws_size,
                              hipStream_t stream) {
    const float* x  = (const float*)d_in[0];
    const float* Ws = (const float*)d_in[2];
    const float* bs = (const float*)d_in[3];
    const float* Wp = (const float*)d_in[4];
    const float* bp = (const float*)d_in[5];
    const float* Wo = (const float*)d_in[6];
    const float* bo = (const float*)d_in[7];
    float* out = (float*)d_out;

    float* space = (float*)d_ws;                         // N*4
    float* prop  = space + (size_t)N_TOTAL * 4;          // N*64
    int*   kidx  = (int*)(prop + (size_t)N_TOTAL * 64);  // 32*N
    float* kw    = (float*)(kidx + (size_t)KNN * N_TOTAL);
    float* fmean = kw + (size_t)KNN * N_TOTAL;           // N*64
    float* fmax  = fmean + (size_t)N_TOTAL * 64;         // N*64
    float*    part_d = fmean;                            // alias (dead until k_agg)
    int*      part_i = (int*)fmax;
    unsigned* g_thr  = (unsigned*)(fmax + (size_t)N_TOTAL * 64);  // N*4 B

    hipMemsetAsync(g_thr, 0x7f, N_TOTAL * sizeof(unsigned), stream);

    k_linear<<<N_TOTAL / 16, 256, 0, stream>>>(x, Wp, bp, Ws, bs, prop, space);
    k_knn1  <<<(N_TOTAL / QB) * 2, 256, 0, stream>>>((const float4*)space, g_thr, part_d, part_i);
    k_knn2  <<<N_TOTAL / 256, 256, 0, stream>>>(part_d, part_i, kidx, kw);
    k_agg   <<<N_TOTAL / 4, 256, 0, stream>>>(prop, kidx, kw, fmean, fmax);
    k_out   <<<N_TOTAL / 16, 256, 0, stream>>>(x, fmean, fmax, Wo, bo, out);
}

// Round 5
// 700.220 us; speedup vs baseline: 1.0015x; 1.0015x over previous
//
#include <hip/hip_runtime.h>
#include <math.h>

#define N_TOTAL 40960
#define M_EV    4096
#define KNN     32
#define FEAT    192   // CIN + 2*PDIM

__device__ __forceinline__ float dot4f(float4 a, float4 b) {
    return fmaf(a.w, b.w, fmaf(a.z, b.z, fmaf(a.y, b.y, a.x * b.x)));
}

// ---------------------------------------------------------------------------
// Register-resident top-K list.
//  * storage: plain C arrays -> after full unroll every index is a compile-time
//    constant, so SROA splits them into 64 independent scalar vregs (NO 32-wide
//    register tuples -- ext_vector_type(32) made the allocator spill whole
//    tuples in rounds 3/4: VGPR_Count=64 + 55MB scratch WRITE_SIZE signature).
//  * max slot tracked as a ONE-HOT MASK, never an index: the per-element select
//    tests (onehot & (1u<<e)) against a constant, so no dynamic indexing is
//    ever introduced (round 2's e==maxpos form defeated SROA -> scratch).
// ---------------------------------------------------------------------------
__device__ __forceinline__ void list_rescan(const float ld[KNN], float &curmax, unsigned &onehot)
{
    float t0[16];
#pragma unroll
    for (int e = 0; e < 16; ++e) t0[e] = fmaxf(ld[2*e], ld[2*e+1]);
    float t1[8];
#pragma unroll
    for (int e = 0; e < 8; ++e) t1[e] = fmaxf(t0[2*e], t0[2*e+1]);
    float t2[4];
#pragma unroll
    for (int e = 0; e < 4; ++e) t2[e] = fmaxf(t1[2*e], t1[2*e+1]);
    float m = fmaxf(fmaxf(t2[0], t2[1]), fmaxf(t2[2], t2[3]));
    unsigned msk = 0u;
#pragma unroll
    for (int e = 0; e < KNN; ++e) msk |= (ld[e] == m) ? (1u << e) : 0u;
    curmax = m;
    onehot = msk & (0u - msk);          // lowest set bit, as a mask (no index!)
}

__device__ __forceinline__ void list_insert(float ld[KNN], int li[KNN],
                                            float &curmax, unsigned &onehot,
                                            float d, int ix)
{
#pragma unroll
    for (int e = 0; e < KNN; ++e) {
        bool s = (onehot & (1u << e)) != 0u;
        ld[e] = s ? d  : ld[e];
        li[e] = s ? ix : li[e];
    }
    list_rescan(ld, curmax, onehot);
}

// ---------------------------------------------------------------------------
// Kernel 1: space = x@W_space + b_space  [N,4];  prop = x@W_prop + b_prop [N,64]
// ---------------------------------------------------------------------------
__global__ __launch_bounds__(256) void k_linear(
    const float* __restrict__ x,
    const float* __restrict__ Wp, const float* __restrict__ bp,
    const float* __restrict__ Ws, const float* __restrict__ bs,
    float* __restrict__ prop, float* __restrict__ space)
{
    __shared__ float xs[16 * 64];
    const int t = threadIdx.x;
    const int rowbase = blockIdx.x * 16;

    {
        float4 v = *(const float4*)(x + rowbase * 64 + t * 4);
        *(float4*)(xs + t * 4) = v;
    }
    __syncthreads();

    const int j  = t & 63;
    const int rg = t >> 6;
    float a0 = 0.f, a1 = 0.f, a2 = 0.f, a3 = 0.f;
#pragma unroll 8
    for (int c = 0; c < 64; ++c) {
        float w = Wp[c * 64 + j];
        a0 = fmaf(xs[(rg * 4 + 0) * 64 + c], w, a0);
        a1 = fmaf(xs[(rg * 4 + 1) * 64 + c], w, a1);
        a2 = fmaf(xs[(rg * 4 + 2) * 64 + c], w, a2);
        a3 = fmaf(xs[(rg * 4 + 3) * 64 + c], w, a3);
    }
    const float bj = bp[j];
    prop[(rowbase + rg * 4 + 0) * 64 + j] = a0 + bj;
    prop[(rowbase + rg * 4 + 1) * 64 + j] = a1 + bj;
    prop[(rowbase + rg * 4 + 2) * 64 + j] = a2 + bj;
    prop[(rowbase + rg * 4 + 3) * 64 + j] = a3 + bj;

    if (t < 64) {
        const int r = t >> 2, s = t & 3;
        float a = 0.f;
#pragma unroll 8
        for (int c = 0; c < 64; ++c)
            a = fmaf(xs[r * 64 + c], Ws[c * 4 + s], a);
        space[(rowbase + r) * 4 + s] = a + bs[s];
    }
}

// ---------------------------------------------------------------------------
// Kernel 2a: per-half exact partial kNN (structure identical to round 4;
// only the list representation and launch bounds changed).
// __launch_bounds__(256,1): min-waves/EU=1 so the register allocator never
// spills to chase occupancy (suspected contributor to rounds 2-4's cap at 64).
// ---------------------------------------------------------------------------
#define QB    64
#define CHUNK 512
#define KTILE 64
#define QCAP  16

__global__ __launch_bounds__(256, 1) void k_knn1(
    const float4* __restrict__ space4,
    unsigned* __restrict__ g_thr,
    float* __restrict__ part_d, int* __restrict__ part_i)
{
    __shared__ float4   s_c[4 * KTILE];      // 4096 B
    __shared__ float    s_sq[4 * KTILE];     // 1024 B
    __shared__ float    s_bd[QCAP * 256];    // 16384 B (aliased as merge pool_d)
    __shared__ int      s_bi[QCAP * 256];    // 16384 B (aliased as merge pool_i)
    __shared__ unsigned s_thr[QB];           // 256 B

    const int t = threadIdx.x;
    const int w = t >> 6;
    const int l = t & 63;
    const int grp  = blockIdx.x >> 1;
    const int half = blockIdx.x & 1;
    const int qbase = grp * QB;
    const int q = qbase + l;
    const int ebase = (qbase / M_EV) * M_EV;
    const int cbase0 = half * 2048 + w * CHUNK;

    if (t < QB) s_thr[t] = 0x7f800000u;
    __syncthreads();

    const float4 qc = space4[q];
    const float sqq = dot4f(qc, qc);

    float ld[KNN]; int li[KNN];
#pragma unroll
    for (int e = 0; e < KNN; ++e) { ld[e] = INFINITY; li[e] = 0; }
    float curmax = INFINITY; unsigned onehot = 1u;
    int cnt = 0;
    float thrA = INFINITY;

    float4 nx = space4[ebase + cbase0 + l];

#pragma unroll 1
    for (int tb = 0; tb < CHUNK / KTILE; ++tb) {
        const int cb = cbase0 + tb * KTILE;
        s_c[w * KTILE + l]  = nx;
        s_sq[w * KTILE + l] = dot4f(nx, nx);
        if (tb + 1 < CHUNK / KTILE)
            nx = space4[ebase + cb + KTILE + l];
        thrA = fminf(curmax, __uint_as_float(s_thr[l]));

#pragma unroll 1
        for (int jj = 0; jj < KTILE; jj += 4) {
            float d[4];
#pragma unroll
            for (int u = 0; u < 4; ++u) {
                float4 c = s_c[w * KTILE + jj + u];
                d[u] = fmaf(-2.0f, dot4f(qc, c), sqq + s_sq[w * KTILE + jj + u]);
            }
#pragma unroll
            for (int u = 0; u < 4; ++u) {
                if (d[u] < thrA) {                 // strict <: earlier idx wins ties
                    s_bd[cnt * 256 + t] = d[u];
                    s_bi[cnt * 256 + t] = cb + jj + u;
                    cnt++;
                }
            }
            if (__any(cnt > QCAP - 4)) {           // wave-collective packed drain
                float gate = fminf(curmax, __uint_as_float(s_thr[l]));
#pragma unroll 1
                for (int b = 0; b < cnt; ++b) {
                    float dd = s_bd[b * 256 + t];
                    if (dd < gate) {
                        list_insert(ld, li, curmax, onehot, dd, s_bi[b * 256 + t]);
                        gate = fminf(curmax, gate);
                    }
                }
                cnt = 0;
                if (curmax < 3.0e38f) {
                    unsigned mb = __float_as_uint(fmaxf(curmax, 0.0f));
                    atomicMin(&s_thr[l], mb);
                    unsigned old = atomicMin(&g_thr[q], mb);   // publish + fresh read
                    atomicMin(&s_thr[l], old);
                }
                thrA = fminf(curmax, __uint_as_float(s_thr[l]));
            }
        }
    }
    {   // final drain
        float gate = fminf(curmax, __uint_as_float(s_thr[l]));
#pragma unroll 1
        for (int b = 0; b < cnt; ++b) {
            float dd = s_bd[b * 256 + t];
            if (dd < gate) {
                list_insert(ld, li, curmax, onehot, dd, s_bi[b * 256 + t]);
                gate = fminf(curmax, gate);
            }
        }
    }

    // ---- hierarchical in-block merge (pool aliases s_bd/s_bi) ----
    __syncthreads();
    if (w >= 2) {
#pragma unroll
        for (int e = 0; e < KNN; ++e) {
            s_bd[((w - 2) * KNN + e) * 64 + l] = ld[e];
            s_bi[((w - 2) * KNN + e) * 64 + l] = li[e];
        }
    }
    __syncthreads();
    if (w < 2) {
#pragma unroll 1
        for (int j = 0; j < KNN; ++j) {
            float dd = s_bd[(w * KNN + j) * 64 + l];
            if (dd < curmax)
                list_insert(ld, li, curmax, onehot, dd, s_bi[(w * KNN + j) * 64 + l]);
        }
    }
    __syncthreads();
    if (w == 1) {
#pragma unroll
        for (int e = 0; e < KNN; ++e) {
            s_bd[e * 64 + l] = ld[e];
            s_bi[e * 64 + l] = li[e];
        }
    }
    __syncthreads();
    if (w == 0) {
#pragma unroll 1
        for (int j = 0; j < KNN; ++j) {
            float dd = s_bd[j * 64 + l];
            if (dd < curmax)
                list_insert(ld, li, curmax, onehot, dd, s_bi[j * 64 + l]);
        }
        const int q2h = (q << 1) | half;
#pragma unroll
        for (int e = 0; e < KNN; ++e) {
            part_d[e * (N_TOTAL * 2) + q2h] = ld[e];
            part_i[e * (N_TOTAL * 2) + q2h] = ebase + li[e];
        }
    }
}

// ---------------------------------------------------------------------------
// Kernel 2b: merge the two per-half top-32 partials -> exact top-32 + weights.
// ---------------------------------------------------------------------------
__global__ __launch_bounds__(256, 1) void k_knn2(
    const float* __restrict__ part_d, const int* __restrict__ part_i,
    int* __restrict__ knn_idx, float* __restrict__ knn_w)
{
    const int q  = blockIdx.x * 256 + threadIdx.x;
    const int q2 = q << 1;

    float ld[KNN]; int li[KNN];
#pragma unroll
    for (int e = 0; e < KNN; ++e) {
        ld[e] = part_d[e * (N_TOTAL * 2) + q2];
        li[e] = part_i[e * (N_TOTAL * 2) + q2];
    }
    float curmax; unsigned onehot;
    list_rescan(ld, curmax, onehot);

#pragma unroll 1
    for (int j = 0; j < KNN; ++j) {
        float dd = part_d[j * (N_TOTAL * 2) + q2 + 1];
        if (dd < curmax)
            list_insert(ld, li, curmax, onehot, dd, part_i[j * (N_TOTAL * 2) + q2 + 1]);
    }

#pragma unroll
    for (int e = 0; e < KNN; ++e) {
        knn_idx[e * N_TOTAL + q] = li[e];
        knn_w[e * N_TOTAL + q]   = __expf(-10.0f * fmaxf(ld[e], 0.0f));
    }
}

// ---------------------------------------------------------------------------
// Kernel 3: weighted gather + mean/max over K
// ---------------------------------------------------------------------------
__global__ __launch_bounds__(256) void k_agg(
    const float* __restrict__ prop,
    const int* __restrict__ knn_idx, const float* __restrict__ knn_w,
    float* __restrict__ fmean, float* __restrict__ fmax)
{
    const int t = threadIdx.x;
    const int p = t & 63;
    const int q = blockIdx.x * 4 + (t >> 6);

    float acc = 0.f, mx = -INFINITY;
#pragma unroll 8
    for (int e = 0; e < KNN; ++e) {
        int   ix = knn_idx[e * N_TOTAL + q];
        float w  = knn_w[e * N_TOTAL + q];
        float g  = w * prop[(size_t)ix * 64 + p];
        acc += g;
        mx = fmaxf(mx, g);
    }
    fmean[(size_t)q * 64 + p] = acc * (1.0f / 32.0f);
    fmax[(size_t)q * 64 + p]  = mx;
}

// ---------------------------------------------------------------------------
// Kernel 4: out = relu([x | fmean | fmax] @ W_out + b_out)
// ---------------------------------------------------------------------------
__global__ __launch_bounds__(256) void k_out(
    const float* __restrict__ x,
    const float* __restrict__ fmean, const float* __restrict__ fmax,
    const float* __restrict__ Wo, const float* __restrict__ bo,
    float* __restrict__ out)
{
    __shared__ float fs[16 * FEAT];
    const int t = threadIdx.x;
    const int qbase = blockIdx.x * 16;

#pragma unroll
    for (int u = 0; u < 12; ++u) {
        int f = u * 256 + t;
        int r = f / FEAT;
        int i = f - r * FEAT;
        float v;
        if (i < 64)        v = x[(size_t)(qbase + r) * 64 + i];
        else if (i < 128)  v = fmean[(size_t)(qbase + r) * 64 + (i - 64)];
        else               v = fmax[(size_t)(qbase + r) * 64 + (i - 128)];
        fs[f] = v;
    }
    __syncthreads();

    const int c  = t & 127;
    const int rg = t >> 7;
    float acc[8] = {0.f, 0.f, 0.f, 0.f, 0.f, 0.f, 0.f, 0.f};

#pragma unroll 4
    for (int i = 0; i < FEAT; ++i) {
        float w = Wo[i * 128 + c];
#pragma unroll
        for (int r = 0; r < 8; ++r)
            acc[r] = fmaf(fs[(rg * 8 + r) * FEAT + i], w, acc[r]);
    }
    const float bc = bo[c];
#pragma unroll
    for (int r = 0; r < 8; ++r)
        out[(size_t)(qbase + rg * 8 + r) * 128 + c] = fmaxf(acc[r] + bc, 0.0f);
}

// ---------------------------------------------------------------------------
extern "C" void kernel_launch(void* const* d_in, const int* in_sizes, int n_in,
                              void* d_out, int out_size, void* d_ws, size_t ws_size,
                              hipStream_t stream) {
    const float* x  = (const float*)d_in[0];
    const float* Ws = (const float*)d_in[2];
    const float* bs = (const float*)d_in[3];
    const float* Wp = (const float*)d_in[4];
    const float* bp = (const float*)d_in[5];
    const float* Wo = (const float*)d_in[6];
    const float* bo = (const float*)d_in[7];
    float* out = (float*)d_out;

    float* space = (float*)d_ws;                         // N*4
    float* prop  = space + (size_t)N_TOTAL * 4;          // N*64
    int*   kidx  = (int*)(prop + (size_t)N_TOTAL * 64);  // 32*N
    float* kw    = (float*)(kidx + (size_t)KNN * N_TOTAL);
    float* fmean = kw + (size_t)KNN * N_TOTAL;           // N*64
    float* fmax  = fmean + (size_t)N_TOTAL * 64;         // N*64
    float*    part_d = fmean;                            // alias (dead until k_agg)
    int*      part_i = (int*)fmax;
    unsigned* g_thr  = (unsigned*)(fmax + (size_t)N_TOTAL * 64);  // N*4 B

    hipMemsetAsync(g_thr, 0x7f, N_TOTAL * sizeof(unsigned), stream);

    k_linear<<<N_TOTAL / 16, 256, 0, stream>>>(x, Wp, bp, Ws, bs, prop, space);
    k_knn1  <<<(N_TOTAL / QB) * 2, 256, 0, stream>>>((const float4*)space, g_thr, part_d, part_i);
    k_knn2  <<<N_TOTAL / 256, 256, 0, stream>>>(part_d, part_i, kidx, kw);
    k_agg   <<<N_TOTAL / 4, 256, 0, stream>>>(prop, kidx, kw, fmean, fmax);
    k_out   <<<N_TOTAL / 16, 256, 0, stream>>>(x, fmean, fmax, Wo, bo, out);
}

// Round 6
// 266.229 us; speedup vs baseline: 2.6342x; 2.6301x over previous
//
#include <hip/hip_runtime.h>
#include <math.h>

#define N_TOTAL 40960
#define M_EV    4096
#define KNN     32
#define FEAT    192   // CIN + 2*PDIM

__device__ __forceinline__ float dot4f(float4 a, float4 b) {
    return fmaf(a.w, b.w, fmaf(a.z, b.z, fmaf(a.y, b.y, a.x * b.x)));
}

// ---------------------------------------------------------------------------
// Kernel 1: space = x@W_space + b_space  [N,4];  prop = x@W_prop + b_prop [N,64]
// ---------------------------------------------------------------------------
__global__ __launch_bounds__(256) void k_linear(
    const float* __restrict__ x,
    const float* __restrict__ Wp, const float* __restrict__ bp,
    const float* __restrict__ Ws, const float* __restrict__ bs,
    float* __restrict__ prop, float* __restrict__ space)
{
    __shared__ float xs[16 * 64];
    const int t = threadIdx.x;
    const int rowbase = blockIdx.x * 16;

    {
        float4 v = *(const float4*)(x + rowbase * 64 + t * 4);
        *(float4*)(xs + t * 4) = v;
    }
    __syncthreads();

    const int j  = t & 63;
    const int rg = t >> 6;
    float a0 = 0.f, a1 = 0.f, a2 = 0.f, a3 = 0.f;
#pragma unroll 8
    for (int c = 0; c < 64; ++c) {
        float w = Wp[c * 64 + j];
        a0 = fmaf(xs[(rg * 4 + 0) * 64 + c], w, a0);
        a1 = fmaf(xs[(rg * 4 + 1) * 64 + c], w, a1);
        a2 = fmaf(xs[(rg * 4 + 2) * 64 + c], w, a2);
        a3 = fmaf(xs[(rg * 4 + 3) * 64 + c], w, a3);
    }
    const float bj = bp[j];
    prop[(rowbase + rg * 4 + 0) * 64 + j] = a0 + bj;
    prop[(rowbase + rg * 4 + 1) * 64 + j] = a1 + bj;
    prop[(rowbase + rg * 4 + 2) * 64 + j] = a2 + bj;
    prop[(rowbase + rg * 4 + 3) * 64 + j] = a3 + bj;

    if (t < 64) {
        const int r = t >> 2, s = t & 3;
        float a = 0.f;
#pragma unroll 8
        for (int c = 0; c < 64; ++c)
            a = fmaf(xs[r * 64 + c], Ws[c * 4 + s], a);
        space[(rowbase + r) * 4 + s] = a + bs[s];
    }
}

// ---------------------------------------------------------------------------
// Kernel 2: exact kNN via threshold-compact-sort. NO per-thread top-K lists
// (rounds 2-5: every list representation spilled; VGPR pinned at 64 + 34 MB
// scratch WRITE_SIZE).
//   Wave = 2 queries; block = 8 waves = 16 queries sharing candidate tiles.
//   Pass 1: distances + per-lane min over the lane's 64-candidate slice.
//           T = 32nd-smallest lane-min (shuffle bitonic + shfl(31)).
//           Guarantee: the 32 smallest lane minima are 32 DISTINCT candidates
//           with d<=T  =>  V32 <= T  =>  top-32 subset of {d<=T}.  Exact.
//   Pass 2: recompute d (identical fma chain => bitwise equal), compact all
//           d<=T into per-query LDS buffer (expected ~43 entries).
//   Select: pad to 64, register shuffle-bitonic sort of (d,idx) lex-ascending;
//           cnt in (64,128]: LDS bitonic-128; cnt>128: flag -> k_fix kernel.
// ---------------------------------------------------------------------------
#define QPB   16
#define TILEC 1024
#define CCAP  128

__global__ __launch_bounds__(512, 1) void k_knn(
    const float4* __restrict__ space4,
    int* __restrict__ knn_idx, float* __restrict__ knn_w,
    int* __restrict__ bad)
{
    __shared__ float4 s_c[TILEC];        // 16384 B
    __shared__ float  s_sq[TILEC];       //  4096 B
    __shared__ float  s_cd[QPB * CCAP];  //  8192 B
    __shared__ int    s_ci[QPB * CCAP];  //  8192 B
    __shared__ int    s_cnt[QPB];        //    64 B   => 36928 B, 4 blocks/CU

    const int t = threadIdx.x;
    const int w = t >> 6;
    const int l = t & 63;
    const int qb = blockIdx.x * QPB;
    const int ebase = (qb / M_EV) * M_EV;
    const int q0 = qb + 2 * w;
    const int q1 = q0 + 1;

    if (t < QPB) s_cnt[t] = 0;

    const float4 qc0 = space4[q0];
    const float4 qc1 = space4[q1];
    const float sqq0 = dot4f(qc0, qc0);
    const float sqq1 = dot4f(qc1, qc1);

    float mn0 = INFINITY, mn1 = INFINITY;

    // ---- pass 1: lane minima ----
#pragma unroll 1
    for (int tile = 0; tile < M_EV / TILEC; ++tile) {
        __syncthreads();
#pragma unroll
        for (int u = 0; u < TILEC / 512; ++u) {
            int ci = u * 512 + t;
            float4 c = space4[ebase + tile * TILEC + ci];
            s_c[ci] = c; s_sq[ci] = dot4f(c, c);
        }
        __syncthreads();
#pragma unroll 4
        for (int j = 0; j < TILEC / 64; ++j) {
            int ci = j * 64 + l;
            float4 c = s_c[ci]; float sc = s_sq[ci];
            mn0 = fminf(mn0, fmaf(-2.0f, dot4f(qc0, c), sqq0 + sc));
            mn1 = fminf(mn1, fmaf(-2.0f, dot4f(qc1, c), sqq1 + sc));
        }
    }

    // ---- T = 32nd smallest of the 64 lane minima (both queries) ----
    float v0 = mn0, v1 = mn1;
#pragma unroll
    for (int k = 2; k <= 64; k <<= 1) {
#pragma unroll
        for (int j = k >> 1; j >= 1; j >>= 1) {
            float p0 = __shfl_xor(v0, j, 64);
            float p1 = __shfl_xor(v1, j, 64);
            bool tmn = (((l & k) == 0) == ((l & j) == 0));
            v0 = tmn ? fminf(v0, p0) : fmaxf(v0, p0);
            v1 = tmn ? fminf(v1, p1) : fmaxf(v1, p1);
        }
    }
    const float T0 = __shfl(v0, 31, 64);
    const float T1 = __shfl(v1, 31, 64);

    // ---- pass 2: compact d<=T ----
#pragma unroll 1
    for (int tile = 0; tile < M_EV / TILEC; ++tile) {
        __syncthreads();
#pragma unroll
        for (int u = 0; u < TILEC / 512; ++u) {
            int ci = u * 512 + t;
            float4 c = space4[ebase + tile * TILEC + ci];
            s_c[ci] = c; s_sq[ci] = dot4f(c, c);
        }
        __syncthreads();
#pragma unroll 2
        for (int j = 0; j < TILEC / 64; ++j) {
            int ci = j * 64 + l;
            float4 c = s_c[ci]; float sc = s_sq[ci];
            float d0 = fmaf(-2.0f, dot4f(qc0, c), sqq0 + sc);
            float d1 = fmaf(-2.0f, dot4f(qc1, c), sqq1 + sc);
            if (d0 <= T0) {
                int p = atomicAdd(&s_cnt[2 * w], 1);
                if (p < CCAP) { s_cd[(2*w)*CCAP + p] = d0; s_ci[(2*w)*CCAP + p] = tile*TILEC + ci; }
            }
            if (d1 <= T1) {
                int p = atomicAdd(&s_cnt[2 * w + 1], 1);
                if (p < CCAP) { s_cd[(2*w+1)*CCAP + p] = d1; s_ci[(2*w+1)*CCAP + p] = tile*TILEC + ci; }
            }
        }
    }
    // (own wave wrote its own compact region; DS ops are in-order per wave)

    // ---- exact select per query ----
#pragma unroll 1
    for (int s = 0; s < 2; ++s) {
        const int qi = 2 * w + s;
        const int q  = qb + qi;
        const int cnt = s_cnt[qi];                 // wave-uniform
        if (cnt > CCAP) {                          // ~never: fallback kernel
            if (l == 0) bad[q] = 1;
            continue;
        }
        if (cnt <= 64) {
            float d = (l < cnt) ? s_cd[qi * CCAP + l] : INFINITY;
            int   i = (l < cnt) ? s_ci[qi * CCAP + l] : 0x7FFFFFFF;
#pragma unroll
            for (int k = 2; k <= 64; k <<= 1) {
#pragma unroll
                for (int j = k >> 1; j >= 1; j >>= 1) {
                    float pd = __shfl_xor(d, j, 64);
                    int   pi = __shfl_xor(i, j, 64);
                    bool tmn  = (((l & k) == 0) == ((l & j) == 0));
                    bool plt  = (pd < d) || (pd == d && pi < i);
                    bool keep = tmn ? plt : !plt;
                    d = keep ? pd : d;
                    i = keep ? pi : i;
                }
            }
            if (l < KNN) {
                knn_idx[q * KNN + l] = ebase + i;
                knn_w[q * KNN + l]   = __expf(-10.0f * fmaxf(d, 0.0f));
            }
        } else {
            // pad to 128, LDS bitonic (1 pair/lane/stage)
            for (int p = cnt + l; p < CCAP; p += 64) {
                s_cd[qi * CCAP + p] = INFINITY;
                s_ci[qi * CCAP + p] = 0x7FFFFFFF;
            }
#pragma unroll 1
            for (int k = 2; k <= 128; k <<= 1) {
#pragma unroll 1
                for (int j = k >> 1; j >= 1; j >>= 1) {
                    int i0 = ((l & ~(j - 1)) << 1) | (l & (j - 1));
                    int i1 = i0 | j;
                    float dA = s_cd[qi*CCAP + i0], dB = s_cd[qi*CCAP + i1];
                    int   iA = s_ci[qi*CCAP + i0], iB = s_ci[qi*CCAP + i1];
                    bool up = ((i0 & k) == 0);
                    bool sw = up ? ((dB < dA) || (dB == dA && iB < iA))
                                 : ((dA < dB) || (dA == dB && iA < iB));
                    if (sw) {
                        s_cd[qi*CCAP + i0] = dB; s_cd[qi*CCAP + i1] = dA;
                        s_ci[qi*CCAP + i0] = iB; s_ci[qi*CCAP + i1] = iA;
                    }
                }
            }
            if (l < KNN) {
                float d = s_cd[qi * CCAP + l];
                int   i = s_ci[qi * CCAP + l];
                knn_idx[q * KNN + l] = ebase + i;
                knn_w[q * KNN + l]   = __expf(-10.0f * fmaxf(d, 0.0f));
            }
        }
    }
}

// ---------------------------------------------------------------------------
// Kernel 2b: exact fallback for flagged queries (expected to never execute
// beyond the flag check). Scratch arrays are fine here.
// ---------------------------------------------------------------------------
__global__ __launch_bounds__(256) void k_fix(
    const float4* __restrict__ space4, const int* __restrict__ bad,
    int* __restrict__ knn_idx, float* __restrict__ knn_w)
{
    const int q = blockIdx.x * 256 + threadIdx.x;
    if (!bad[q]) return;
    const int eb = (q / M_EV) * M_EV;
    float4 qc = space4[q];
    float sqq = dot4f(qc, qc);
    float ld[KNN]; int li[KNN];
    for (int e = 0; e < KNN; ++e) { ld[e] = INFINITY; li[e] = 0; }
    float cm = INFINITY; int mp = 0;
    for (int c = 0; c < M_EV; ++c) {
        float4 cc = space4[eb + c];
        float d = fmaf(-2.0f, dot4f(qc, cc), sqq + dot4f(cc, cc));
        if (d < cm) {
            ld[mp] = d; li[mp] = c;
            cm = ld[0]; mp = 0;
            for (int e = 1; e < KNN; ++e) if (ld[e] > cm) { cm = ld[e]; mp = e; }
        }
    }
    for (int e = 0; e < KNN; ++e) {
        knn_idx[q * KNN + e] = eb + li[e];
        knn_w[q * KNN + e]   = __expf(-10.0f * fmaxf(ld[e], 0.0f));
    }
}

// ---------------------------------------------------------------------------
// Kernel 3: weighted gather + mean/max over K  (knn layout now [q*32+e])
// ---------------------------------------------------------------------------
__global__ __launch_bounds__(256) void k_agg(
    const float* __restrict__ prop,
    const int* __restrict__ knn_idx, const float* __restrict__ knn_w,
    float* __restrict__ fmean, float* __restrict__ fmax)
{
    const int t = threadIdx.x;
    const int p = t & 63;
    const int q = blockIdx.x * 4 + (t >> 6);

    float acc = 0.f, mx = -INFINITY;
#pragma unroll 8
    for (int e = 0; e < KNN; ++e) {
        int   ix = knn_idx[q * KNN + e];     // wave-uniform load
        float w  = knn_w[q * KNN + e];
        float g  = w * prop[(size_t)ix * 64 + p];
        acc += g;
        mx = fmaxf(mx, g);
    }
    fmean[(size_t)q * 64 + p] = acc * (1.0f / 32.0f);
    fmax[(size_t)q * 64 + p]  = mx;
}

// ---------------------------------------------------------------------------
// Kernel 4: out = relu([x | fmean | fmax] @ W_out + b_out)
// ---------------------------------------------------------------------------
__global__ __launch_bounds__(256) void k_out(
    const float* __restrict__ x,
    const float* __restrict__ fmean, const float* __restrict__ fmax,
    const float* __restrict__ Wo, const float* __restrict__ bo,
    float* __restrict__ out)
{
    __shared__ float fs[16 * FEAT];
    const int t = threadIdx.x;
    const int qbase = blockIdx.x * 16;

#pragma unroll
    for (int u = 0; u < 12; ++u) {
        int f = u * 256 + t;
        int r = f / FEAT;
        int i = f - r * FEAT;
        float v;
        if (i < 64)        v = x[(size_t)(qbase + r) * 64 + i];
        else if (i < 128)  v = fmean[(size_t)(qbase + r) * 64 + (i - 64)];
        else               v = fmax[(size_t)(qbase + r) * 64 + (i - 128)];
        fs[f] = v;
    }
    __syncthreads();

    const int c  = t & 127;
    const int rg = t >> 7;
    float acc[8] = {0.f, 0.f, 0.f, 0.f, 0.f, 0.f, 0.f, 0.f};

#pragma unroll 4
    for (int i = 0; i < FEAT; ++i) {
        float w = Wo[i * 128 + c];
#pragma unroll
        for (int r = 0; r < 8; ++r)
            acc[r] = fmaf(fs[(rg * 8 + r) * FEAT + i], w, acc[r]);
    }
    const float bc = bo[c];
#pragma unroll
    for (int r = 0; r < 8; ++r)
        out[(size_t)(qbase + rg * 8 + r) * 128 + c] = fmaxf(acc[r] + bc, 0.0f);
}

// ---------------------------------------------------------------------------
extern "C" void kernel_launch(void* const* d_in, const int* in_sizes, int n_in,
                              void* d_out, int out_size, void* d_ws, size_t ws_size,
                              hipStream_t stream) {
    const float* x  = (const float*)d_in[0];
    const float* Ws = (const float*)d_in[2];
    const float* bs = (const float*)d_in[3];
    const float* Wp = (const float*)d_in[4];
    const float* bp = (const float*)d_in[5];
    const float* Wo = (const float*)d_in[6];
    const float* bo = (const float*)d_in[7];
    float* out = (float*)d_out;

    float* space = (float*)d_ws;                          // N*4
    float* prop  = space + (size_t)N_TOTAL * 4;           // N*64
    int*   kidx  = (int*)(prop + (size_t)N_TOTAL * 64);   // N*32
    float* kw    = (float*)(kidx + (size_t)N_TOTAL * KNN);// N*32
    float* fmean = kw + (size_t)N_TOTAL * KNN;            // N*64
    float* fmax  = fmean + (size_t)N_TOTAL * 64;          // N*64
    int*   bad   = (int*)(fmax + (size_t)N_TOTAL * 64);   // N

    hipMemsetAsync(bad, 0, N_TOTAL * sizeof(int), stream);

    k_linear<<<N_TOTAL / 16, 256, 0, stream>>>(x, Wp, bp, Ws, bs, prop, space);
    k_knn   <<<N_TOTAL / QPB, 512, 0, stream>>>((const float4*)space, kidx, kw, bad);
    k_fix   <<<N_TOTAL / 256, 256, 0, stream>>>((const float4*)space, bad, kidx, kw);
    k_agg   <<<N_TOTAL / 4, 256, 0, stream>>>(prop, kidx, kw, fmean, fmax);
    k_out   <<<N_TOTAL / 16, 256, 0, stream>>>(x, fmean, fmax, Wo, bo, out);
}

// Round 7
// 250.428 us; speedup vs baseline: 2.8004x; 1.0631x over previous
//
#include <hip/hip_runtime.h>
#include <math.h>

#define N_TOTAL 40960
#define M_EV    4096
#define KNN     32
#define FEAT    192   // CIN + 2*PDIM

__device__ __forceinline__ float dot4f(float4 a, float4 b) {
    return fmaf(a.w, b.w, fmaf(a.z, b.z, fmaf(a.y, b.y, a.x * b.x)));
}

// ---------------------------------------------------------------------------
// Kernel 1: space = x@W_space + b_space  [N,4];  prop = x@W_prop + b_prop [N,64]
// ---------------------------------------------------------------------------
__global__ __launch_bounds__(256) void k_linear(
    const float* __restrict__ x,
    const float* __restrict__ Wp, const float* __restrict__ bp,
    const float* __restrict__ Ws, const float* __restrict__ bs,
    float* __restrict__ prop, float* __restrict__ space)
{
    __shared__ float xs[16 * 64];
    const int t = threadIdx.x;
    const int rowbase = blockIdx.x * 16;

    {
        float4 v = *(const float4*)(x + rowbase * 64 + t * 4);
        *(float4*)(xs + t * 4) = v;
    }
    __syncthreads();

    const int j  = t & 63;
    const int rg = t >> 6;
    float a0 = 0.f, a1 = 0.f, a2 = 0.f, a3 = 0.f;
#pragma unroll 8
    for (int c = 0; c < 64; ++c) {
        float w = Wp[c * 64 + j];
        a0 = fmaf(xs[(rg * 4 + 0) * 64 + c], w, a0);
        a1 = fmaf(xs[(rg * 4 + 1) * 64 + c], w, a1);
        a2 = fmaf(xs[(rg * 4 + 2) * 64 + c], w, a2);
        a3 = fmaf(xs[(rg * 4 + 3) * 64 + c], w, a3);
    }
    const float bj = bp[j];
    prop[(rowbase + rg * 4 + 0) * 64 + j] = a0 + bj;
    prop[(rowbase + rg * 4 + 1) * 64 + j] = a1 + bj;
    prop[(rowbase + rg * 4 + 2) * 64 + j] = a2 + bj;
    prop[(rowbase + rg * 4 + 3) * 64 + j] = a3 + bj;

    if (t < 64) {
        const int r = t >> 2, s = t & 3;
        float a = 0.f;
#pragma unroll 8
        for (int c = 0; c < 64; ++c)
            a = fmaf(xs[r * 64 + c], Ws[c * 4 + s], a);
        space[(rowbase + r) * 4 + s] = a + bs[s];
    }
}

// ---------------------------------------------------------------------------
// Kernel 2: exact kNN, threshold-compact-sort (round 6 structure), now
// 4 queries/wave: the s_c/s_sq LDS read + address math per candidate is
// amortized over 4 distance computations instead of 2.
// s_ci stored as ushort (local idx <= 4095). bad[] written unconditionally
// (replaces the memset dispatch).
// ---------------------------------------------------------------------------
#define QPB   32
#define TILEC 1024
#define CCAP  128

__global__ __launch_bounds__(512, 1) void k_knn(
    const float4* __restrict__ space4,
    int* __restrict__ knn_idx, float* __restrict__ knn_w,
    int* __restrict__ bad)
{
    __shared__ float4  s_c[TILEC];        // 16384 B
    __shared__ float   s_sq[TILEC];       //  4096 B
    __shared__ float   s_cd[QPB * CCAP];  // 16384 B
    __shared__ ushort  s_ci[QPB * CCAP];  //  8192 B
    __shared__ int     s_cnt[QPB];        //   128 B  => 45184 B, 3 blocks/CU

    const int t = threadIdx.x;
    const int w = t >> 6;
    const int l = t & 63;
    const int qb = blockIdx.x * QPB;
    const int ebase = (qb / M_EV) * M_EV;

    if (t < QPB) s_cnt[t] = 0;

    float4 qcs[4];
    float  sqq[4];
#pragma unroll
    for (int s = 0; s < 4; ++s) {
        qcs[s] = space4[qb + w * 4 + s];
        sqq[s] = dot4f(qcs[s], qcs[s]);
    }

    float mn[4];
#pragma unroll
    for (int s = 0; s < 4; ++s) mn[s] = INFINITY;

    // ---- pass 1: per-lane slice minima (slice = {j*64+l}) ----
#pragma unroll 1
    for (int tile = 0; tile < M_EV / TILEC; ++tile) {
        __syncthreads();
#pragma unroll
        for (int u = 0; u < TILEC / 512; ++u) {
            int ci = u * 512 + t;
            float4 c = space4[ebase + tile * TILEC + ci];
            s_c[ci] = c; s_sq[ci] = dot4f(c, c);
        }
        __syncthreads();
#pragma unroll 4
        for (int j = 0; j < TILEC / 64; ++j) {
            int ci = j * 64 + l;
            float4 c = s_c[ci]; float sc = s_sq[ci];
#pragma unroll
            for (int s = 0; s < 4; ++s)
                mn[s] = fminf(mn[s], fmaf(-2.0f, dot4f(qcs[s], c), sqq[s] + sc));
        }
    }

    // ---- T[s] = 32nd smallest of the 64 slice minima ----
    float v0 = mn[0], v1 = mn[1], v2 = mn[2], v3 = mn[3];
#pragma unroll
    for (int k = 2; k <= 64; k <<= 1) {
#pragma unroll
        for (int j = k >> 1; j >= 1; j >>= 1) {
            float p0 = __shfl_xor(v0, j, 64);
            float p1 = __shfl_xor(v1, j, 64);
            float p2 = __shfl_xor(v2, j, 64);
            float p3 = __shfl_xor(v3, j, 64);
            bool tmn = (((l & k) == 0) == ((l & j) == 0));
            v0 = tmn ? fminf(v0, p0) : fmaxf(v0, p0);
            v1 = tmn ? fminf(v1, p1) : fmaxf(v1, p1);
            v2 = tmn ? fminf(v2, p2) : fmaxf(v2, p2);
            v3 = tmn ? fminf(v3, p3) : fmaxf(v3, p3);
        }
    }
    float T[4];
    T[0] = __shfl(v0, 31, 64); T[1] = __shfl(v1, 31, 64);
    T[2] = __shfl(v2, 31, 64); T[3] = __shfl(v3, 31, 64);

    // ---- pass 2: compact d<=T (identical fma chain => bitwise equal) ----
#pragma unroll 1
    for (int tile = 0; tile < M_EV / TILEC; ++tile) {
        __syncthreads();
#pragma unroll
        for (int u = 0; u < TILEC / 512; ++u) {
            int ci = u * 512 + t;
            float4 c = space4[ebase + tile * TILEC + ci];
            s_c[ci] = c; s_sq[ci] = dot4f(c, c);
        }
        __syncthreads();
#pragma unroll 2
        for (int j = 0; j < TILEC / 64; ++j) {
            int ci = j * 64 + l;
            float4 c = s_c[ci]; float sc = s_sq[ci];
            float d[4];
#pragma unroll
            for (int s = 0; s < 4; ++s)
                d[s] = fmaf(-2.0f, dot4f(qcs[s], c), sqq[s] + sc);
#pragma unroll
            for (int s = 0; s < 4; ++s) {
                if (d[s] <= T[s]) {
                    int p = atomicAdd(&s_cnt[w * 4 + s], 1);
                    if (p < CCAP) {
                        s_cd[(w * 4 + s) * CCAP + p] = d[s];
                        s_ci[(w * 4 + s) * CCAP + p] = (ushort)(tile * TILEC + ci);
                    }
                }
            }
        }
    }
    // own wave wrote its own compact region; DS ops in-order per wave.

    // ---- exact select per query ----
#pragma unroll 1
    for (int s = 0; s < 4; ++s) {
        const int qi = w * 4 + s;
        const int q  = qb + qi;
        const int cnt = s_cnt[qi];                 // wave-uniform
        if (l == 0) bad[q] = (cnt > CCAP) ? 1 : 0;
        if (cnt > CCAP) continue;                  // ~never: fallback kernel
        if (cnt <= 64) {
            float d = (l < cnt) ? s_cd[qi * CCAP + l] : INFINITY;
            int   i = (l < cnt) ? (int)s_ci[qi * CCAP + l] : 65535;
#pragma unroll
            for (int k = 2; k <= 64; k <<= 1) {
#pragma unroll
                for (int j = k >> 1; j >= 1; j >>= 1) {
                    float pd = __shfl_xor(d, j, 64);
                    int   pi = __shfl_xor(i, j, 64);
                    bool tmn  = (((l & k) == 0) == ((l & j) == 0));
                    bool plt  = (pd < d) || (pd == d && pi < i);
                    bool keep = tmn ? plt : !plt;
                    d = keep ? pd : d;
                    i = keep ? pi : i;
                }
            }
            if (l < KNN) {
                knn_idx[q * KNN + l] = ebase + i;
                knn_w[q * KNN + l]   = __expf(-10.0f * fmaxf(d, 0.0f));
            }
        } else {
            for (int p = cnt + l; p < CCAP; p += 64) {
                s_cd[qi * CCAP + p] = INFINITY;
                s_ci[qi * CCAP + p] = (ushort)65535;
            }
#pragma unroll 1
            for (int k = 2; k <= 128; k <<= 1) {
#pragma unroll 1
                for (int j = k >> 1; j >= 1; j >>= 1) {
                    int i0 = ((l & ~(j - 1)) << 1) | (l & (j - 1));
                    int i1 = i0 | j;
                    float dA = s_cd[qi*CCAP + i0], dB = s_cd[qi*CCAP + i1];
                    int   iA = (int)s_ci[qi*CCAP + i0], iB = (int)s_ci[qi*CCAP + i1];
                    bool up = ((i0 & k) == 0);
                    bool sw = up ? ((dB < dA) || (dB == dA && iB < iA))
                                 : ((dA < dB) || (dA == dB && iA < iB));
                    if (sw) {
                        s_cd[qi*CCAP + i0] = dB; s_cd[qi*CCAP + i1] = dA;
                        s_ci[qi*CCAP + i0] = (ushort)iB; s_ci[qi*CCAP + i1] = (ushort)iA;
                    }
                }
            }
            if (l < KNN) {
                float d = s_cd[qi * CCAP + l];
                int   i = (int)s_ci[qi * CCAP + l];
                knn_idx[q * KNN + l] = ebase + i;
                knn_w[q * KNN + l]   = __expf(-10.0f * fmaxf(d, 0.0f));
            }
        }
    }
}

// ---------------------------------------------------------------------------
// Kernel 2b: exact fallback for flagged queries (expected never to fire).
// ---------------------------------------------------------------------------
__global__ __launch_bounds__(256) void k_fix(
    const float4* __restrict__ space4, const int* __restrict__ bad,
    int* __restrict__ knn_idx, float* __restrict__ knn_w)
{
    const int q = blockIdx.x * 256 + threadIdx.x;
    if (!bad[q]) return;
    const int eb = (q / M_EV) * M_EV;
    float4 qc = space4[q];
    float sqq = dot4f(qc, qc);
    float ld[KNN]; int li[KNN];
    for (int e = 0; e < KNN; ++e) { ld[e] = INFINITY; li[e] = 0; }
    float cm = INFINITY; int mp = 0;
    for (int c = 0; c < M_EV; ++c) {
        float4 cc = space4[eb + c];
        float d = fmaf(-2.0f, dot4f(qc, cc), sqq + dot4f(cc, cc));
        if (d < cm) {
            ld[mp] = d; li[mp] = c;
            cm = ld[0]; mp = 0;
            for (int e = 1; e < KNN; ++e) if (ld[e] > cm) { cm = ld[e]; mp = e; }
        }
    }
    for (int e = 0; e < KNN; ++e) {
        knn_idx[q * KNN + e] = eb + li[e];
        knn_w[q * KNN + e]   = __expf(-10.0f * fmaxf(ld[e], 0.0f));
    }
}

// ---------------------------------------------------------------------------
// Kernel 3 (fused agg+out): per 16-query block,
//   A: stage feat = [x | mean_k(w*prop) | max_k(w*prop)] TRANSPOSED in LDS
//      (fs2[i*18 + r], stride 18 floats: 8B-aligned b64 row-pair reads,
//       agg writes land on 16 distinct banks (4-way, 1.58x) instead of 2)
//   B: out = relu(feat @ W_out + b_out), W_out staged in 48-row LDS chunks.
// Removes the fmean/fmax HBM round-trip (42 MB) and one dispatch.
// ---------------------------------------------------------------------------
#define FSTR 18

__global__ __launch_bounds__(256) void k_tail(
    const float* __restrict__ x, const float* __restrict__ prop,
    const int* __restrict__ knn_idx, const float* __restrict__ knn_w,
    const float* __restrict__ Wo, const float* __restrict__ bo,
    float* __restrict__ out)
{
    __shared__ float fs2[FEAT * FSTR];   // 13824 B
    __shared__ float s_w[48 * 128];      // 24576 B  => 38400 B, 4 blocks/CU

    const int t = threadIdx.x;
    const int qb = blockIdx.x * 16;

    // A1: x transpose: fs2[i*18 + r] = x[(qb+r)*64 + i]
    {
        const int r = t >> 4, c4 = (t & 15) * 4;
        float4 v = *(const float4*)(x + (size_t)(qb + r) * 64 + c4);
        fs2[(c4 + 0) * FSTR + r] = v.x;
        fs2[(c4 + 1) * FSTR + r] = v.y;
        fs2[(c4 + 2) * FSTR + r] = v.z;
        fs2[(c4 + 3) * FSTR + r] = v.w;
    }

    // A2: aggregation (4 rounds of 4 queries; lane p = prop channel)
    {
        const int p = t & 63;
#pragma unroll 1
        for (int s = 0; s < 4; ++s) {
            const int r = s * 4 + (t >> 6);
            const int q = qb + r;
            float acc = 0.f, mx = -INFINITY;
#pragma unroll 8
            for (int e = 0; e < KNN; ++e) {
                int   ix = knn_idx[q * KNN + e];     // wave-uniform
                float wv = knn_w[q * KNN + e];
                float g  = wv * prop[(size_t)ix * 64 + p];
                acc += g;
                mx = fmaxf(mx, g);
            }
            fs2[(64 + p) * FSTR + r]  = acc * (1.0f / 32.0f);
            fs2[(128 + p) * FSTR + r] = mx;
        }
    }

    // B: GEMM. thread = (2 rows: rg=t>>5) x (4 cols: c4=(t&31)*4)
    const int rg = t >> 5;
    const int c4 = (t & 31) * 4;
    float acc0[4] = {0.f, 0.f, 0.f, 0.f};
    float acc1[4] = {0.f, 0.f, 0.f, 0.f};

#pragma unroll 1
    for (int cc = 0; cc < 4; ++cc) {
        __syncthreads();                  // fs2 ready (cc=0) / prev chunk done
#pragma unroll
        for (int u = 0; u < 6; ++u) {     // stage 48x128 W chunk (24 B/thread)
            int fi = u * 1024 + t * 4;
            *(float4*)(s_w + fi) = *(const float4*)(Wo + (size_t)cc * 48 * 128 + fi);
        }
        __syncthreads();
#pragma unroll 4
        for (int ii = 0; ii < 48; ++ii) {
            int i = cc * 48 + ii;
            float2 f = *(const float2*)(fs2 + i * FSTR + rg * 2);
            float4 wv = *(const float4*)(s_w + ii * 128 + c4);
            acc0[0] = fmaf(f.x, wv.x, acc0[0]); acc0[1] = fmaf(f.x, wv.y, acc0[1]);
            acc0[2] = fmaf(f.x, wv.z, acc0[2]); acc0[3] = fmaf(f.x, wv.w, acc0[3]);
            acc1[0] = fmaf(f.y, wv.x, acc1[0]); acc1[1] = fmaf(f.y, wv.y, acc1[1]);
            acc1[2] = fmaf(f.y, wv.z, acc1[2]); acc1[3] = fmaf(f.y, wv.w, acc1[3]);
        }
    }

    const float4 bc = *(const float4*)(bo + c4);
    float4 o0, o1;
    o0.x = fmaxf(acc0[0] + bc.x, 0.f); o0.y = fmaxf(acc0[1] + bc.y, 0.f);
    o0.z = fmaxf(acc0[2] + bc.z, 0.f); o0.w = fmaxf(acc0[3] + bc.w, 0.f);
    o1.x = fmaxf(acc1[0] + bc.x, 0.f); o1.y = fmaxf(acc1[1] + bc.y, 0.f);
    o1.z = fmaxf(acc1[2] + bc.z, 0.f); o1.w = fmaxf(acc1[3] + bc.w, 0.f);
    *(float4*)(out + (size_t)(qb + rg * 2 + 0) * 128 + c4) = o0;
    *(float4*)(out + (size_t)(qb + rg * 2 + 1) * 128 + c4) = o1;
}

// ---------------------------------------------------------------------------
extern "C" void kernel_launch(void* const* d_in, const int* in_sizes, int n_in,
                              void* d_out, int out_size, void* d_ws, size_t ws_size,
                              hipStream_t stream) {
    const float* x  = (const float*)d_in[0];
    const float* Ws = (const float*)d_in[2];
    const float* bs = (const float*)d_in[3];
    const float* Wp = (const float*)d_in[4];
    const float* bp = (const float*)d_in[5];
    const float* Wo = (const float*)d_in[6];
    const float* bo = (const float*)d_in[7];
    float* out = (float*)d_out;

    float* space = (float*)d_ws;                          // N*4
    float* prop  = space + (size_t)N_TOTAL * 4;           // N*64
    int*   kidx  = (int*)(prop + (size_t)N_TOTAL * 64);   // N*32
    float* kw    = (float*)(kidx + (size_t)N_TOTAL * KNN);// N*32
    int*   bad   = (int*)(kw + (size_t)N_TOTAL * KNN);    // N

    k_linear<<<N_TOTAL / 16, 256, 0, stream>>>(x, Wp, bp, Ws, bs, prop, space);
    k_knn   <<<N_TOTAL / QPB, 512, 0, stream>>>((const float4*)space, kidx, kw, bad);
    k_fix   <<<N_TOTAL / 256, 256, 0, stream>>>((const float4*)space, bad, kidx, kw);
    k_tail  <<<N_TOTAL / 16, 256, 0, stream>>>(x, prop, kidx, kw, Wo, bo, out);
}